// Round 5
// baseline (113.884 us; speedup 1.0000x reference)
//
#include <hip/hip_runtime.h>
#include <hip/hip_bf16.h>
#include <cstdint>

#define N_ROWS 4096
#define N_CLS  8192
#define D_EMB  512
#define K_DIM  1024   // bytes per row: [x^2 s-channel 512][2x ps-channel 512]

using f32x4 = __attribute__((ext_vector_type(4))) float;

__device__ __forceinline__ float softplus_f(float v) {
  return (v > 20.f) ? v : log1pf(expf(v));
}

// pack 4 f32 -> 4 fp8 e4m3 (OCP) in one uint, RNE via HW cvt
__device__ __forceinline__ unsigned int pack4_e4m3(float a, float b, float c, float d) {
  int lo = __builtin_amdgcn_cvt_pk_fp8_f32(a, b, 0, false);   // word0
  return (unsigned int)__builtin_amdgcn_cvt_pk_fp8_f32(c, d, lo, true); // word1
}

__device__ __forceinline__ float e4m3_to_f(unsigned char v) {
  int e = (v >> 3) & 15, m = v & 7;
  float f;
  if (e) f = __uint_as_float((unsigned int)((e + 120) << 23) | ((unsigned int)m << 20));
  else   f = (float)m * 0.001953125f;   // m * 2^-9
  return (v & 0x80) ? -f : f;
}

// block-wide sum for 256 threads (4 waves); re-entrant (syncs guard the LDS)
__device__ __forceinline__ float block_sum256(float v) {
  __shared__ float red[4];
  #pragma unroll
  for (int o = 32; o; o >>= 1) v += __shfl_xor(v, o);
  __syncthreads();
  if ((threadIdx.x & 63) == 0) red[threadIdx.x >> 6] = v;
  __syncthreads();
  return red[0] + red[1] + red[2] + red[3];
}

__device__ __forceinline__ void global_to_lds16(const void* g, void* l) {
  const __attribute__((address_space(1))) unsigned int* gp =
      reinterpret_cast<const __attribute__((address_space(1))) unsigned int*>(
          reinterpret_cast<uintptr_t>(g));
  __attribute__((address_space(3))) unsigned int* lp =
      reinterpret_cast<__attribute__((address_space(3))) unsigned int*>(
          reinterpret_cast<uintptr_t>(l));
  __builtin_amdgcn_global_load_lds(gp, lp, 16, 0, 0);
}

// ---------------------------------------------------------------------------
// K1: per-class prep. Bmat[c, 0:512] = fp8(s_c), Bmat[c, 512:1024] = fp8(P*s).
//     tvec[c] = sum_d P^2 s ;  klc[c] = sum_d 0.5*(1/s + pn^2 - 1 + log s)
// ---------------------------------------------------------------------------
__global__ __launch_bounds__(256) void k_proxy(const float* __restrict__ proxies,
                                               const float* __restrict__ sigmas_inv,
                                               unsigned char* __restrict__ Bmat,
                                               float* __restrict__ tvec,
                                               float* __restrict__ klc) {
  const int c = blockIdx.x;
  const int tid = threadIdx.x;
  const float* p  = proxies    + (size_t)c * D_EMB;
  const float* si = sigmas_inv + (size_t)c * D_EMB;
  float2 p2 = ((const float2*)p)[tid];
  float2 s2 = ((const float2*)si)[tid];
  float ss = block_sum256(p2.x * p2.x + p2.y * p2.y);
  float invn = 1.0f / fmaxf(sqrtf(ss), 1e-12f);
  float tc = 0.f, kl = 0.f;
  {
    float sp = softplus_f(s2.x), s = sp * sp, pn = p2.x * invn, P = 3.0f * pn;
    tc += P * P * s;
    kl += 0.5f * (1.0f / s + pn * pn - 1.0f + 2.0f * logf(sp));
    sp = softplus_f(s2.y); s = sp * sp; pn = p2.y * invn; P = 3.0f * pn;
    tc += P * P * s;
    kl += 0.5f * (1.0f / s + pn * pn - 1.0f + 2.0f * logf(sp));
  }
  tc = block_sum256(tc);
  kl = block_sum256(kl);
  if (tid == 0) { tvec[c] = tc; klc[c] = kl; }

  unsigned int* brow = (unsigned int*)(Bmat + (size_t)c * K_DIM);
  if (tid < 128) {                       // s channel, d = 4*tid..+3
    float4 sv = ((const float4*)si)[tid];
    float a0 = softplus_f(sv.x), a1 = softplus_f(sv.y),
          a2 = softplus_f(sv.z), a3 = softplus_f(sv.w);
    brow[tid] = pack4_e4m3(a0 * a0, a1 * a1, a2 * a2, a3 * a3);
  } else {                               // P*s channel
    int t = tid - 128;
    float4 pv = ((const float4*)p)[t];
    float4 sv = ((const float4*)si)[t];
    float a0 = softplus_f(sv.x), a1 = softplus_f(sv.y),
          a2 = softplus_f(sv.z), a3 = softplus_f(sv.w);
    float k3 = 3.0f * invn;
    brow[128 + t] = pack4_e4m3(k3 * pv.x * a0 * a0, k3 * pv.y * a1 * a1,
                               k3 * pv.z * a2 * a2, k3 * pv.w * a3 * a3);
  }
}

// ---------------------------------------------------------------------------
// K2: per-row prep. Amat[n, 0:512] = fp8(-Xn^2), Amat[n, 512:1024] = fp8(2*Xn).
// ---------------------------------------------------------------------------
__global__ __launch_bounds__(256) void k_xprep(const float* __restrict__ X,
                                               unsigned char* __restrict__ Amat) {
  const int n = blockIdx.x;
  const int tid = threadIdx.x;
  const float* x = X + (size_t)n * D_EMB;
  float2 x2 = ((const float2*)x)[tid];
  float ss = block_sum256(x2.x * x2.x + x2.y * x2.y);
  float invn = 3.0f / fmaxf(sqrtf(ss), 1e-12f);   // SCALE folded in
  unsigned int* arow = (unsigned int*)(Amat + (size_t)n * K_DIM);
  if (tid < 128) {
    float4 xv = ((const float4*)x)[tid];
    float v0 = xv.x * invn, v1 = xv.y * invn, v2 = xv.z * invn, v3 = xv.w * invn;
    arow[tid] = pack4_e4m3(-v0 * v0, -v1 * v1, -v2 * v2, -v3 * v3);
  } else {
    int t = tid - 128;
    float4 xv = ((const float4*)x)[t];
    arow[128 + t] = pack4_e4m3(2.0f * xv.x * invn, 2.0f * xv.y * invn,
                               2.0f * xv.z * invn, 2.0f * xv.w * invn);
  }
}

// ---------------------------------------------------------------------------
// K3: 256x128-tile fp8 MFMA GEMM (K=1024 bytes), double-buffered LDS,
//     prefetch-issue-before-compute. 8 waves = 4M x 2N, per-wave 64x64 out
//     (acc=64 VGPR -> 4 waves/SIMD, 2 blocks/CU). XOR swizzle on bits 4-6
//     keyed by row-pair (2-way bank = free); inverse swizzle on global source
//     (16B-granule compatible). Fused per-row max/sumexp epilogue.
// ---------------------------------------------------------------------------
__global__ __launch_bounds__(512, 4) void k_gemm_lse(const unsigned char* __restrict__ Amat,
                                                     const unsigned char* __restrict__ Bmat,
                                                     const float* __restrict__ tvec,
                                                     float* __restrict__ Pm,
                                                     float* __restrict__ Psum) {
  union SMem {
    struct { unsigned char As[2][16384]; unsigned char Bs[2][8192]; } st; // 48 KB
    float ms[256][2][2];   // 4 KB epilogue combine (overlaps As[0]; last tile reads buf 1)
  };
  __shared__ SMem sm;
  const int tid  = threadIdx.x;
  const int lane = tid & 63;
  const int wave = tid >> 6;
  const int wr = wave >> 1, wc = wave & 1;          // 4x2 wave grid; per-wave 64x64 out
  // T1: chunked XCD swizzle. nwg=1024, 128 consecutive per XCD.
  const int swz  = ((int)blockIdx.x & 7) * 128 + ((int)blockIdx.x >> 3);
  const int rt   = swz & 15;                        // 16 row tiles (256 rows)
  const int ct   = swz >> 4;                        // 64 col tiles (128 cols)
  const int row0 = rt * 256;
  const int col0 = ct * 128;

  f32x4 acc[4][4];
  #pragma unroll
  for (int i = 0; i < 4; ++i)
    #pragma unroll
    for (int j = 0; j < 4; ++j) acc[i][j] = (f32x4){0.f, 0.f, 0.f, 0.f};

  const int arow = wr * 64 + (lane & 15);           // + mi*16
  const int bcol = wc * 64 + (lane & 15);           // + ni*16
  const int kb8  = (lane >> 4) * 8;                 // k-byte within 32-chunk

  auto stage = [&](int buf, int ko) {
    #pragma unroll
    for (int rep = 0; rep < 2; ++rep) {             // A: 16 KB = 2 x (512*16B)
      int f  = rep * 8192 + tid * 16;
      int sf = f ^ (((f >> 7) & 7) << 4);
      global_to_lds16(Amat + (size_t)(row0 + (sf >> 6)) * K_DIM + ko + (sf & 63),
                      &sm.st.As[buf][f]);
    }
    {                                               // B: 8 KB = 1 x (512*16B)
      int f  = tid * 16;
      int sf = f ^ (((f >> 7) & 7) << 4);
      global_to_lds16(Bmat + (size_t)(col0 + (sf >> 6)) * K_DIM + ko + (sf & 63),
                      &sm.st.Bs[buf][f]);
    }
  };
  auto ld64 = [&](const unsigned char* base, int row, int kb) -> long {
    int f = row * 64 + kb;
    return *(const long*)(base + (f ^ (((f >> 7) & 7) << 4)));
  };

  stage(0, 0);
  __syncthreads();
  for (int t = 0; t < 16; ++t) {
    if (t < 15) stage((t + 1) & 1, (t + 1) * 64);   // issue next-tile loads FIRST
    const unsigned char* Ab = sm.st.As[t & 1];
    const unsigned char* Bb = sm.st.Bs[t & 1];
    __builtin_amdgcn_s_setprio(1);
    #pragma unroll
    for (int ks = 0; ks < 64; ks += 32) {
      long a[4], b[4];
      #pragma unroll
      for (int mi = 0; mi < 4; ++mi) a[mi] = ld64(Ab, arow + mi * 16, ks + kb8);
      #pragma unroll
      for (int ni = 0; ni < 4; ++ni) b[ni] = ld64(Bb, bcol + ni * 16, ks + kb8);
      #pragma unroll
      for (int mi = 0; mi < 4; ++mi)
        #pragma unroll
        for (int ni = 0; ni < 4; ++ni)
          acc[mi][ni] = __builtin_amdgcn_mfma_f32_16x16x32_fp8_fp8(a[mi], b[ni], acc[mi][ni], 0, 0, 0);
    }
    __builtin_amdgcn_s_setprio(0);
    __syncthreads();   // drains staging vmcnt AFTER compute: latency hidden
  }

  // ---- in-register epilogue: per-row max / sumexp over this wave's 64 cols.
  // C/D layout: col = lane&15, row = (lane>>4)*4 + j.
  float tc[4];
  #pragma unroll
  for (int ni = 0; ni < 4; ++ni)
    tc[ni] = tvec[col0 + wc * 64 + ni * 16 + (lane & 15)];

  #pragma unroll
  for (int mi = 0; mi < 4; ++mi) {
    #pragma unroll
    for (int j = 0; j < 4; ++j) {
      float z0 = acc[mi][0][j] - tc[0];
      float z1 = acc[mi][1][j] - tc[1];
      float z2 = acc[mi][2][j] - tc[2];
      float z3 = acc[mi][3][j] - tc[3];
      float m = fmaxf(fmaxf(z0, z1), fmaxf(z2, z3));
      #pragma unroll
      for (int o = 1; o < 16; o <<= 1) m = fmaxf(m, __shfl_xor(m, o));
      float s = __expf(z0 - m) + __expf(z1 - m) + __expf(z2 - m) + __expf(z3 - m);
      #pragma unroll
      for (int o = 1; o < 16; o <<= 1) s += __shfl_xor(s, o);
      if ((lane & 15) == 0) {
        int rloc = wr * 64 + mi * 16 + ((lane >> 4) << 2) + j;
        sm.ms[rloc][wc][0] = m;
        sm.ms[rloc][wc][1] = s;
      }
    }
  }
  __syncthreads();
  if (tid < 256) {
    float m0 = sm.ms[tid][0][0], s0 = sm.ms[tid][0][1];
    float m1 = sm.ms[tid][1][0], s1 = sm.ms[tid][1][1];
    float M = fmaxf(m0, m1);
    float S = s0 * __expf(m0 - M) + s1 * __expf(m1 - M);
    Pm  [(size_t)(row0 + tid) * 64 + ct] = M;
    Psum[(size_t)(row0 + tid) * 64 + ct] = S;
  }
}

// ---------------------------------------------------------------------------
// K4: exact target logit per row: tgt[n] = A[n]·B[T[n]] - t[T[n]]
//     (same quantized fp8 operands as the GEMM, f32 accumulate)
// ---------------------------------------------------------------------------
__global__ __launch_bounds__(256) void k_target(const unsigned char* __restrict__ Amat,
                                                const unsigned char* __restrict__ Bmat,
                                                const float* __restrict__ tvec,
                                                const int* __restrict__ T,
                                                float* __restrict__ tgt) {
  const int lane = threadIdx.x & 63;
  const int n = blockIdx.x * 4 + (threadIdx.x >> 6);
  const int c = T[n];
  uint4 av = *(const uint4*)(Amat + (size_t)n * K_DIM + lane * 16);
  uint4 bv = *(const uint4*)(Bmat + (size_t)c * K_DIM + lane * 16);
  const unsigned char* ab = (const unsigned char*)&av;
  const unsigned char* bb = (const unsigned char*)&bv;
  float s = 0.f;
  #pragma unroll
  for (int i = 0; i < 16; ++i) s += e4m3_to_f(ab[i]) * e4m3_to_f(bb[i]);
  #pragma unroll
  for (int o = 32; o; o >>= 1) s += __shfl_xor(s, o);
  if (lane == 0) tgt[n] = s - tvec[c];
}

// ---------------------------------------------------------------------------
// K5a: 64-block reduce. Block b: rows [b*64, b*64+64) -> ce partial;
//      classes [b*128, b*128+128) -> kl partial. 64 LSE partials per row.
// ---------------------------------------------------------------------------
__global__ __launch_bounds__(256) void k_red(const float* __restrict__ Pm,
                                             const float* __restrict__ Psum,
                                             const float* __restrict__ tgt,
                                             const float* __restrict__ klc,
                                             float* __restrict__ cep,
                                             float* __restrict__ klp) {
  const int b = blockIdx.x;
  const int tid = threadIdx.x;
  const int n = b * 64 + (tid >> 2);
  const int q = tid & 3;
  const float4* pm4 = (const float4*)(Pm   + (size_t)n * 64 + q * 16);
  const float4* ps4 = (const float4*)(Psum + (size_t)n * 64 + q * 16);
  float4 pm[4], ps[4];
  #pragma unroll
  for (int i = 0; i < 4; ++i) { pm[i] = pm4[i]; ps[i] = ps4[i]; }
  float m = -3.0e38f;
  #pragma unroll
  for (int i = 0; i < 4; ++i)
    m = fmaxf(m, fmaxf(fmaxf(pm[i].x, pm[i].y), fmaxf(pm[i].z, pm[i].w)));
  m = fmaxf(m, __shfl_xor(m, 1));
  m = fmaxf(m, __shfl_xor(m, 2));
  float S = 0.f;
  #pragma unroll
  for (int i = 0; i < 4; ++i) {
    S += ps[i].x * __expf(pm[i].x - m) + ps[i].y * __expf(pm[i].y - m)
       + ps[i].z * __expf(pm[i].z - m) + ps[i].w * __expf(pm[i].w - m);
  }
  S += __shfl_xor(S, 1);
  S += __shfl_xor(S, 2);
  float ce = (q == 0) ? (m + logf(S) - tgt[n]) : 0.f;
  float kl = (tid < 128) ? klc[b * 128 + tid] : 0.f;
  ce = block_sum256(ce);
  kl = block_sum256(kl);
  if (tid == 0) { cep[b] = ce; klp[b] = kl; }
}

// K5b: final combine (1 block, 64 threads)
__global__ __launch_bounds__(64) void k_fin2(const float* __restrict__ cep,
                                             const float* __restrict__ klp,
                                             float* __restrict__ out) {
  const int tid = threadIdx.x;
  float ce = cep[tid], kl = klp[tid];
  #pragma unroll
  for (int o = 32; o; o >>= 1) { ce += __shfl_xor(ce, o); kl += __shfl_xor(kl, o); }
  if (tid == 0) out[0] = ce / (float)N_ROWS + 0.2f * (kl / (float)N_CLS);
}

extern "C" void kernel_launch(void* const* d_in, const int* in_sizes, int n_in,
                              void* d_out, int out_size, void* d_ws, size_t ws_size,
                              hipStream_t stream) {
  const float* X          = (const float*)d_in[0];
  // d_in[1] = indices (unused by the reference loss)
  const int*   T          = (const int*)d_in[2];
  const float* proxies    = (const float*)d_in[3];
  const float* sigmas_inv = (const float*)d_in[4];

  char* ws = (char*)d_ws;
  unsigned char* Amat = (unsigned char*)ws;                            // 4 MiB
  unsigned char* Bmat = (unsigned char*)(ws + (4u << 20));             // 8 MiB
  float* tvec = (float*)(ws + (12u << 20));                            // 32 KiB
  float* klc  = (float*)(ws + (12u << 20) + (32u << 10));              // 32 KiB
  float* Pm   = (float*)(ws + (12u << 20) + (64u << 10));              // 1 MiB
  float* Psum = (float*)(ws + (13u << 20) + (64u << 10));              // 1 MiB
  float* tgt  = (float*)(ws + (14u << 20) + (64u << 10));              // 16 KiB
  float* cep  = (float*)(ws + (14u << 20) + (80u << 10));              // 256 B
  float* klp  = (float*)(ws + (14u << 20) + (84u << 10));              // 256 B
  float* out  = (float*)d_out;

  hipLaunchKernelGGL(k_proxy,    dim3(N_CLS),      dim3(256), 0, stream, proxies, sigmas_inv, Bmat, tvec, klc);
  hipLaunchKernelGGL(k_xprep,    dim3(N_ROWS),     dim3(256), 0, stream, X, Amat);
  hipLaunchKernelGGL(k_gemm_lse, dim3(1024),       dim3(512), 0, stream, Amat, Bmat, tvec, Pm, Psum);
  hipLaunchKernelGGL(k_target,   dim3(N_ROWS / 4), dim3(256), 0, stream, Amat, Bmat, tvec, T, tgt);
  hipLaunchKernelGGL(k_red,      dim3(64),         dim3(256), 0, stream, Pm, Psum, tgt, klc, cep, klp);
  hipLaunchKernelGGL(k_fin2,     dim3(1),          dim3(64),  0, stream, cep, klp, out);
}

// Round 6
// 92.416 us; speedup vs baseline: 1.2323x; 1.2323x over previous
//
#include <hip/hip_runtime.h>
#include <hip/hip_bf16.h>
#include <cstdint>

#define N_ROWS 4096
#define N_CLS  8192
#define D_EMB  512
#define K_DIM  1024   // bytes per row: [x^2 s-channel 512][2x ps-channel 512]

using f32x4 = __attribute__((ext_vector_type(4))) float;

__device__ __forceinline__ float softplus_f(float v) {
  return (v > 20.f) ? v : log1pf(expf(v));
}

// pack 2 f32 -> 2 fp8 e4m3 (OCP, RNE) in low 16 bits
__device__ __forceinline__ unsigned short pack2_e4m3(float a, float b) {
  return (unsigned short)(__builtin_amdgcn_cvt_pk_fp8_f32(a, b, 0, false) & 0xffff);
}

__device__ __forceinline__ float e4m3_to_f(unsigned char v) {
  int e = (v >> 3) & 15, m = v & 7;
  float f;
  if (e) f = __uint_as_float((unsigned int)((e + 120) << 23) | ((unsigned int)m << 20));
  else   f = (float)m * 0.001953125f;   // m * 2^-9
  return (v & 0x80) ? -f : f;
}

// block-wide sum for 256 threads (4 waves); re-entrant (syncs guard the LDS)
__device__ __forceinline__ float block_sum256(float v) {
  __shared__ float red[4];
  #pragma unroll
  for (int o = 32; o; o >>= 1) v += __shfl_xor(v, o);
  __syncthreads();
  if ((threadIdx.x & 63) == 0) red[threadIdx.x >> 6] = v;
  __syncthreads();
  return red[0] + red[1] + red[2] + red[3];
}

__device__ __forceinline__ void global_to_lds16(const void* g, void* l) {
  const __attribute__((address_space(1))) unsigned int* gp =
      reinterpret_cast<const __attribute__((address_space(1))) unsigned int*>(
          reinterpret_cast<uintptr_t>(g));
  __attribute__((address_space(3))) unsigned int* lp =
      reinterpret_cast<__attribute__((address_space(3))) unsigned int*>(
          reinterpret_cast<uintptr_t>(l));
  __builtin_amdgcn_global_load_lds(gp, lp, 16, 0, 0);
}

// ---------------------------------------------------------------------------
// K1: per-class prep. Bmat[c, 0:512] = fp8(s_c), Bmat[c, 512:1024] = fp8(P*s).
//     tvec[c] = sum_d P^2 s ;  klc[c] = sum_d 0.5*(1/s + pn^2 - 1 + log s)
//     One softplus per element; 2 elems/thread.
// ---------------------------------------------------------------------------
__global__ __launch_bounds__(256) void k_proxy(const float* __restrict__ proxies,
                                               const float* __restrict__ sigmas_inv,
                                               unsigned char* __restrict__ Bmat,
                                               float* __restrict__ tvec,
                                               float* __restrict__ klc) {
  const int c = blockIdx.x;
  const int tid = threadIdx.x;
  const float* p  = proxies    + (size_t)c * D_EMB;
  const float* si = sigmas_inv + (size_t)c * D_EMB;
  float2 p2 = ((const float2*)p)[tid];
  float ss = block_sum256(p2.x * p2.x + p2.y * p2.y);
  float invn = 1.0f / fmaxf(sqrtf(ss), 1e-12f);
  float2 s2 = ((const float2*)si)[tid];
  float sp0 = softplus_f(s2.x), sp1 = softplus_f(s2.y);
  float s0 = sp0 * sp0, s1 = sp1 * sp1;
  float pn0 = p2.x * invn, pn1 = p2.y * invn;
  float P0 = 3.0f * pn0, P1 = 3.0f * pn1;
  unsigned short* brow = (unsigned short*)(Bmat + (size_t)c * K_DIM);
  brow[tid]       = pack2_e4m3(s0, s1);
  brow[256 + tid] = pack2_e4m3(P0 * s0, P1 * s1);
  float tc = P0 * P0 * s0 + P1 * P1 * s1;
  float kl = 0.5f * (1.0f / s0 + pn0 * pn0 - 1.0f + 2.0f * logf(sp0))
           + 0.5f * (1.0f / s1 + pn1 * pn1 - 1.0f + 2.0f * logf(sp1));
  tc = block_sum256(tc);
  kl = block_sum256(kl);
  if (tid == 0) { tvec[c] = tc; klc[c] = kl; }
}

// ---------------------------------------------------------------------------
// K2: per-row prep. Amat[n, 0:512] = fp8(-Xn^2), Amat[n, 512:1024] = fp8(2*Xn).
// ---------------------------------------------------------------------------
__global__ __launch_bounds__(256) void k_xprep(const float* __restrict__ X,
                                               unsigned char* __restrict__ Amat) {
  const int n = blockIdx.x;
  const int tid = threadIdx.x;
  const float* x = X + (size_t)n * D_EMB;
  float2 x2 = ((const float2*)x)[tid];
  float ss = block_sum256(x2.x * x2.x + x2.y * x2.y);
  float invn = 3.0f / fmaxf(sqrtf(ss), 1e-12f);   // SCALE folded in
  float v0 = x2.x * invn, v1 = x2.y * invn;
  unsigned short* arow = (unsigned short*)(Amat + (size_t)n * K_DIM);
  arow[tid]       = pack2_e4m3(-v0 * v0, -v1 * v1);
  arow[256 + tid] = pack2_e4m3(2.0f * v0, 2.0f * v1);
}

// ---------------------------------------------------------------------------
// K3: 256x128-tile fp8 MFMA GEMM (K=1024 bytes), 3-slot LDS pipeline with
//     counted vmcnt (T4): per iter {barrier; stage(t+2); vmcnt(6); barrier;
//     ds_read+MFMA}. No main-loop vmcnt(0) drain. Precomputed swizzled LDS
//     offsets (kills per-iter VALU). 8 waves = 4M x 2N, per-wave 64x64 out;
//     2 blocks/CU (72 KB LDS, <=128 VGPR). Fused row max/sumexp epilogue.
// ---------------------------------------------------------------------------
__global__ __launch_bounds__(512, 4) void k_gemm_lse(const unsigned char* __restrict__ Amat,
                                                     const unsigned char* __restrict__ Bmat,
                                                     const float* __restrict__ tvec,
                                                     float* __restrict__ Pm,
                                                     float* __restrict__ Psum) {
  // LDS map: As[3][16384] at 0 ; Bs[3][8192] at 49152 ; total 73728 B.
  // Epilogue ms[256][2][2] overlays As[1] (byte 16384) — disjoint from the
  // last-read slot 0 (As[0]/Bs[0]); guarded by __syncthreads before reads.
  __shared__ __align__(16) unsigned char lds[73728];
  const int tid  = threadIdx.x;
  const int lane = tid & 63;
  const int wave = tid >> 6;
  const int wr = wave >> 1, wc = wave & 1;          // 4x2 wave grid; per-wave 64x64 out
  // T1: chunked XCD swizzle. nwg=1024, 128 consecutive per XCD.
  const int swz  = ((int)blockIdx.x & 7) * 128 + ((int)blockIdx.x >> 3);
  const int rt   = swz & 15;                        // 16 row tiles (256 rows)
  const int ct   = swz >> 4;                        // 64 col tiles (128 cols)
  const int row0 = rt * 256;
  const int col0 = ct * 128;

  f32x4 acc[4][4];
  #pragma unroll
  for (int i = 0; i < 4; ++i)
    #pragma unroll
    for (int j = 0; j < 4; ++j) acc[i][j] = (f32x4){0.f, 0.f, 0.f, 0.f};

  const int arow = wr * 64 + (lane & 15);           // + mi*16
  const int bcol = wc * 64 + (lane & 15);           // + ni*16
  const int kb8  = (lane >> 4) * 8;                 // k-byte within 32-chunk

  // precomputed swizzled LDS read offsets (static-indexed -> stay in VGPRs)
  int offA[4][2], offB[4][2];
  #pragma unroll
  for (int mi = 0; mi < 4; ++mi) {
    #pragma unroll
    for (int s2 = 0; s2 < 2; ++s2) {
      int f = (arow + mi * 16) * 64 + kb8 + s2 * 32;
      offA[mi][s2] = f ^ (((f >> 7) & 7) << 4);
      int g = (bcol + mi * 16) * 64 + kb8 + s2 * 32;
      offB[mi][s2] = g ^ (((g >> 7) & 7) << 4);
    }
  }
  // precomputed per-thread staging pointers (inverse swizzle on global source)
  const int f0 = tid * 16;
  const int f1 = 8192 + tid * 16;
  const int sf0 = f0 ^ (((f0 >> 7) & 7) << 4);
  const int sf1 = f1 ^ (((f1 >> 7) & 7) << 4);
  const unsigned char* gA0 = Amat + (size_t)(row0 + (sf0 >> 6)) * K_DIM + (sf0 & 63);
  const unsigned char* gA1 = Amat + (size_t)(row0 + (sf1 >> 6)) * K_DIM + (sf1 & 63);
  const unsigned char* gB0 = Bmat + (size_t)(col0 + (sf0 >> 6)) * K_DIM + (sf0 & 63);

  auto stg = [&](int slot, int ko) {                // 3 loads/thread in flight
    global_to_lds16(gA0 + ko, lds + slot * 16384 + f0);
    global_to_lds16(gA1 + ko, lds + slot * 16384 + f1);
    global_to_lds16(gB0 + ko, lds + 49152 + slot * 8192 + f0);
  };
  auto compute = [&](int sa, int sb) {
    __builtin_amdgcn_s_setprio(1);
    #pragma unroll
    for (int s2 = 0; s2 < 2; ++s2) {
      long a[4], b[4];
      #pragma unroll
      for (int mi = 0; mi < 4; ++mi) a[mi] = *(const long*)(lds + sa + offA[mi][s2]);
      #pragma unroll
      for (int ni = 0; ni < 4; ++ni) b[ni] = *(const long*)(lds + sb + offB[ni][s2]);
      #pragma unroll
      for (int mi = 0; mi < 4; ++mi)
        #pragma unroll
        for (int ni = 0; ni < 4; ++ni)
          acc[mi][ni] = __builtin_amdgcn_mfma_f32_16x16x32_fp8_fp8(a[mi], b[ni], acc[mi][ni], 0, 0, 0);
    }
    __builtin_amdgcn_s_setprio(0);
  };

  stg(0, 0);
  stg(1, 64);
  // Per iter T: barrier #1 = all waves finished reading slot (T-1) [their
  // MFMAs consumed those ds_reads] -> safe to overwrite it with stage(T+2).
  // vmcnt(NW) = all but the newest NW loads retired -> slot T landed.
  // barrier #2 = slot T's stage-writes (by ALL threads) visible.
#define GITER(T, NW) \
  __builtin_amdgcn_s_barrier(); \
  if ((T) + 2 < 16) stg(((T) + 2) % 3, ((T) + 2) * 64); \
  asm volatile("s_waitcnt vmcnt(" #NW ")" ::: "memory"); \
  __builtin_amdgcn_sched_barrier(0); \
  __builtin_amdgcn_s_barrier(); \
  compute(((T) % 3) * 16384, 49152 + ((T) % 3) * 8192);

  GITER(0, 6)  GITER(1, 6)  GITER(2, 6)  GITER(3, 6)
  GITER(4, 6)  GITER(5, 6)  GITER(6, 6)  GITER(7, 6)
  GITER(8, 6)  GITER(9, 6)  GITER(10, 6) GITER(11, 6)
  GITER(12, 6) GITER(13, 6) GITER(14, 3) GITER(15, 0)
#undef GITER

  // ---- in-register epilogue: per-row max / sumexp over this wave's 64 cols.
  // C/D layout: col = lane&15, row = (lane>>4)*4 + j.
  float (*ms)[2][2] = (float (*)[2][2])(lds + 16384);
  float tc[4];
  #pragma unroll
  for (int ni = 0; ni < 4; ++ni)
    tc[ni] = tvec[col0 + wc * 64 + ni * 16 + (lane & 15)];

  #pragma unroll
  for (int mi = 0; mi < 4; ++mi) {
    #pragma unroll
    for (int j = 0; j < 4; ++j) {
      float z0 = acc[mi][0][j] - tc[0];
      float z1 = acc[mi][1][j] - tc[1];
      float z2 = acc[mi][2][j] - tc[2];
      float z3 = acc[mi][3][j] - tc[3];
      float m = fmaxf(fmaxf(z0, z1), fmaxf(z2, z3));
      #pragma unroll
      for (int o = 1; o < 16; o <<= 1) m = fmaxf(m, __shfl_xor(m, o));
      float s = __expf(z0 - m) + __expf(z1 - m) + __expf(z2 - m) + __expf(z3 - m);
      #pragma unroll
      for (int o = 1; o < 16; o <<= 1) s += __shfl_xor(s, o);
      if ((lane & 15) == 0) {
        int rloc = wr * 64 + mi * 16 + ((lane >> 4) << 2) + j;
        ms[rloc][wc][0] = m;
        ms[rloc][wc][1] = s;
      }
    }
  }
  __syncthreads();
  if (tid < 256) {
    float m0 = ms[tid][0][0], s0 = ms[tid][0][1];
    float m1 = ms[tid][1][0], s1 = ms[tid][1][1];
    float M = fmaxf(m0, m1);
    float S = s0 * __expf(m0 - M) + s1 * __expf(m1 - M);
    Pm  [(size_t)(row0 + tid) * 64 + ct] = M;
    Psum[(size_t)(row0 + tid) * 64 + ct] = S;
  }
}

// ---------------------------------------------------------------------------
// K4: exact target logit per row: tgt[n] = A[n]·B[T[n]] - t[T[n]]
//     (same quantized fp8 operands as the GEMM, f32 accumulate)
// ---------------------------------------------------------------------------
__global__ __launch_bounds__(256) void k_target(const unsigned char* __restrict__ Amat,
                                                const unsigned char* __restrict__ Bmat,
                                                const float* __restrict__ tvec,
                                                const int* __restrict__ T,
                                                float* __restrict__ tgt) {
  const int lane = threadIdx.x & 63;
  const int n = blockIdx.x * 4 + (threadIdx.x >> 6);
  const int c = T[n];
  uint4 av = *(const uint4*)(Amat + (size_t)n * K_DIM + lane * 16);
  uint4 bv = *(const uint4*)(Bmat + (size_t)c * K_DIM + lane * 16);
  const unsigned char* ab = (const unsigned char*)&av;
  const unsigned char* bb = (const unsigned char*)&bv;
  float s = 0.f;
  #pragma unroll
  for (int i = 0; i < 16; ++i) s += e4m3_to_f(ab[i]) * e4m3_to_f(bb[i]);
  #pragma unroll
  for (int o = 32; o; o >>= 1) s += __shfl_xor(s, o);
  if (lane == 0) tgt[n] = s - tvec[c];
}

// ---------------------------------------------------------------------------
// K5a: 256-block reduce. Block b: rows [b*16, b*16+16) -> ce partial
//      (16 lanes/row, 1 float4 each); classes [b*32, b*32+32) -> kl partial.
// ---------------------------------------------------------------------------
__global__ __launch_bounds__(256) void k_red(const float* __restrict__ Pm,
                                             const float* __restrict__ Psum,
                                             const float* __restrict__ tgt,
                                             const float* __restrict__ klc,
                                             float* __restrict__ cep,
                                             float* __restrict__ klp) {
  const int b = blockIdx.x;
  const int tid = threadIdx.x;
  const int n = b * 16 + (tid >> 4);
  const int l4 = tid & 15;
  float4 pm = *(const float4*)(Pm   + (size_t)n * 64 + l4 * 4);
  float4 ps = *(const float4*)(Psum + (size_t)n * 64 + l4 * 4);
  float m = fmaxf(fmaxf(pm.x, pm.y), fmaxf(pm.z, pm.w));
  #pragma unroll
  for (int o = 1; o < 16; o <<= 1) m = fmaxf(m, __shfl_xor(m, o));
  float S = ps.x * __expf(pm.x - m) + ps.y * __expf(pm.y - m)
          + ps.z * __expf(pm.z - m) + ps.w * __expf(pm.w - m);
  #pragma unroll
  for (int o = 1; o < 16; o <<= 1) S += __shfl_xor(S, o);
  float ce = (l4 == 0) ? (m + logf(S) - tgt[n]) : 0.f;
  float kl = (tid < 32) ? klc[b * 32 + tid] : 0.f;
  ce = block_sum256(ce);
  kl = block_sum256(kl);
  if (tid == 0) { cep[b] = ce; klp[b] = kl; }
}

// K5b: final combine (1 block, 256 threads)
__global__ __launch_bounds__(256) void k_fin2(const float* __restrict__ cep,
                                              const float* __restrict__ klp,
                                              float* __restrict__ out) {
  const int tid = threadIdx.x;
  float ce = block_sum256(cep[tid]);
  float kl = block_sum256(klp[tid]);
  if (tid == 0) out[0] = ce / (float)N_ROWS + 0.2f * (kl / (float)N_CLS);
}

extern "C" void kernel_launch(void* const* d_in, const int* in_sizes, int n_in,
                              void* d_out, int out_size, void* d_ws, size_t ws_size,
                              hipStream_t stream) {
  const float* X          = (const float*)d_in[0];
  // d_in[1] = indices (unused by the reference loss)
  const int*   T          = (const int*)d_in[2];
  const float* proxies    = (const float*)d_in[3];
  const float* sigmas_inv = (const float*)d_in[4];

  char* ws = (char*)d_ws;
  unsigned char* Amat = (unsigned char*)ws;                            // 4 MiB
  unsigned char* Bmat = (unsigned char*)(ws + (4u << 20));             // 8 MiB
  float* tvec = (float*)(ws + (12u << 20));                            // 32 KiB
  float* klc  = (float*)(ws + (12u << 20) + (32u << 10));              // 32 KiB
  float* Pm   = (float*)(ws + (12u << 20) + (64u << 10));              // 1 MiB
  float* Psum = (float*)(ws + (13u << 20) + (64u << 10));              // 1 MiB
  float* tgt  = (float*)(ws + (14u << 20) + (64u << 10));              // 16 KiB
  float* cep  = (float*)(ws + (14u << 20) + (80u << 10));              // 1 KiB
  float* klp  = (float*)(ws + (14u << 20) + (84u << 10));              // 1 KiB
  float* out  = (float*)d_out;

  hipLaunchKernelGGL(k_proxy,    dim3(N_CLS),      dim3(256), 0, stream, proxies, sigmas_inv, Bmat, tvec, klc);
  hipLaunchKernelGGL(k_xprep,    dim3(N_ROWS),     dim3(256), 0, stream, X, Amat);
  hipLaunchKernelGGL(k_gemm_lse, dim3(1024),       dim3(512), 0, stream, Amat, Bmat, tvec, Pm, Psum);
  hipLaunchKernelGGL(k_target,   dim3(N_ROWS / 4), dim3(256), 0, stream, Amat, Bmat, tvec, T, tgt);
  hipLaunchKernelGGL(k_red,      dim3(256),        dim3(256), 0, stream, Pm, Psum, tgt, klc, cep, klp);
  hipLaunchKernelGGL(k_fin2,     dim3(1),          dim3(256), 0, stream, cep, klp, out);
}